// Round 2
// baseline (270.057 us; speedup 1.0000x reference)
//
#include <hip/hip_runtime.h>

#define HDIM 4096
#define NIN 17
#define NA 4

// ---- config ----
constexpr int TB = 256;                 // threads per block
constexpr int CPT = 4;                  // columns per thread (one float4)
constexpr int BXC = HDIM / (TB * CPT);  // 4 column groups
constexpr int NCHUNK = 256;             // row chunks
constexpr int RPC = HDIM / NCHUNK;      // 16 rows per chunk

// Kernel A: partial sums of hidden @ (w + alpha*hebb) over row chunks.
// partial[chunk][j] = sum_{i in chunk} hidden[i] * (w[i,j] + alpha[i,j]*hebb[i,j])
__global__ __launch_bounds__(TB)
void k_matvec(const float* __restrict__ w, const float* __restrict__ alpha,
              const float* __restrict__ hebb, const float* __restrict__ hidden,
              float* __restrict__ partial) {
    const int col0 = (blockIdx.x * TB + threadIdx.x) * CPT;
    const int row0 = blockIdx.y * RPC;
    float4 acc = make_float4(0.f, 0.f, 0.f, 0.f);
#pragma unroll 4
    for (int r = 0; r < RPC; ++r) {
        const int i = row0 + r;
        const size_t off = (size_t)i * HDIM + col0;
        const float hv = hidden[i];
        const float4 wv = *(const float4*)(w + off);
        const float4 av = *(const float4*)(alpha + off);
        const float4 bv = *(const float4*)(hebb + off);
        acc.x += hv * (wv.x + av.x * bv.x);
        acc.y += hv * (wv.y + av.y * bv.y);
        acc.z += hv * (wv.z + av.z * bv.z);
        acc.w += hv * (wv.w + av.w * bv.w);
    }
    *(float4*)(partial + (size_t)blockIdx.y * HDIM + col0) = acc;
}

// Kernel B: reduce partials, add i2h(x)+bias, tanh -> h (fp32 to ws and to out)
__global__ __launch_bounds__(256)
void k_hact(const float* __restrict__ partial,
            const float* __restrict__ x, const float* __restrict__ i2h_w,
            const float* __restrict__ i2h_b,
            float* __restrict__ h_f, float* __restrict__ h_out) {
    const int j = blockIdx.x * 256 + threadIdx.x;
    float s = 0.f;
    for (int c = 0; c < NCHUNK; ++c) s += partial[(size_t)c * HDIM + j];
    float z = i2h_b[j] + s;
#pragma unroll
    for (int k = 0; k < NIN; ++k) z += x[k] * i2h_w[j * NIN + k];
    const float h = tanhf(z);
    h_f[j] = h;
    h_out[j] = h;
}

// Kernel C: hebb_new = (1-eta)*hebb + eta*outer(hidden, h); 4 elems/thread.
// hebb_out region starts at element offset 4101 in d_out -> only 4B-aligned,
// so vector loads from hebb (16B-aligned) but scalar dword stores.
__global__ __launch_bounds__(256)
void k_hebb(const float* __restrict__ hebb, const float* __restrict__ hidden,
            const float* __restrict__ h_f, const float* __restrict__ eta,
            float* __restrict__ hebb_out) {
    const size_t m = ((size_t)blockIdx.x * 256 + threadIdx.x) * 4;
    const float e = eta[0];
    const float om = 1.f - e;
    const int i = (int)(m >> 12);          // m / 4096
    const int j = (int)(m & (HDIM - 1));   // m % 4096 (multiple of 4; never crosses a row)
    const float hv = e * hidden[i];
    const float4 hb = *(const float4*)(hebb + m);
    const float4 hj = *(const float4*)(h_f + j);
    hebb_out[m]     = om * hb.x + hv * hj.x;
    hebb_out[m + 1] = om * hb.y + hv * hj.y;
    hebb_out[m + 2] = om * hb.z + hv * hj.z;
    hebb_out[m + 3] = om * hb.w + hv * hj.w;
}

// Kernel D: activout = softmax(h @ h2o_w.T + h2o_b), valueout = h @ h2v_w.T + h2v_b
__global__ __launch_bounds__(256)
void k_heads(const float* __restrict__ h_f,
             const float* __restrict__ h2o_w, const float* __restrict__ h2o_b,
             const float* __restrict__ h2v_w, const float* __restrict__ h2v_b,
             float* __restrict__ out) {
    const int tid = threadIdx.x;
    float acc[NA + 1] = {0.f, 0.f, 0.f, 0.f, 0.f};
    for (int t = 0; t < HDIM / 256; ++t) {
        const int j = t * 256 + tid;
        const float hv = h_f[j];
#pragma unroll
        for (int a = 0; a < NA; ++a) acc[a] += hv * h2o_w[a * HDIM + j];
        acc[NA] += hv * h2v_w[j];
    }
    __shared__ float red[256];
    __shared__ float res[NA + 1];
    for (int a = 0; a < NA + 1; ++a) {
        red[tid] = acc[a];
        __syncthreads();
        for (int sft = 128; sft > 0; sft >>= 1) {
            if (tid < sft) red[tid] += red[tid + sft];
            __syncthreads();
        }
        if (tid == 0) res[a] = red[0];
        __syncthreads();
    }
    if (tid == 0) {
        float o[NA];
        float mx = -1e30f;
        for (int a = 0; a < NA; ++a) { o[a] = res[a] + h2o_b[a]; mx = fmaxf(mx, o[a]); }
        float se = 0.f;
        for (int a = 0; a < NA; ++a) { o[a] = __expf(o[a] - mx); se += o[a]; }
        for (int a = 0; a < NA; ++a) out[a] = o[a] / se;
        out[NA] = res[NA] + h2v_b[0];
    }
}

extern "C" void kernel_launch(void* const* d_in, const int* in_sizes, int n_in,
                              void* d_out, int out_size, void* d_ws, size_t ws_size,
                              hipStream_t stream) {
    const float* x      = (const float*)d_in[0];
    const float* hidden = (const float*)d_in[1];
    const float* hebb   = (const float*)d_in[2];
    const float* i2h_w  = (const float*)d_in[3];
    const float* i2h_b  = (const float*)d_in[4];
    const float* w      = (const float*)d_in[5];
    const float* alpha  = (const float*)d_in[6];
    const float* eta    = (const float*)d_in[7];
    const float* h2o_w  = (const float*)d_in[8];
    const float* h2o_b  = (const float*)d_in[9];
    const float* h2v_w  = (const float*)d_in[10];
    const float* h2v_b  = (const float*)d_in[11];
    float* out = (float*)d_out;

    float* partial = (float*)d_ws;                    // NCHUNK*HDIM floats (4 MB)
    float* h_f = partial + (size_t)NCHUNK * HDIM;     // HDIM floats

    // out layout: activout[4] | valueout[1] | h[4096] | hebb_new[4096*4096]
    float* h_out    = out + 5;
    float* hebb_out = out + 5 + HDIM;

    k_matvec<<<dim3(BXC, NCHUNK), TB, 0, stream>>>(w, alpha, hebb, hidden, partial);
    k_hact<<<HDIM / 256, 256, 0, stream>>>(partial, x, i2h_w, i2h_b, h_f, h_out);
    k_hebb<<<(int)(((size_t)HDIM * HDIM) / 1024), 256, 0, stream>>>(hebb, hidden, h_f, eta, hebb_out);
    k_heads<<<1, 256, 0, stream>>>(h_f, h2o_w, h2o_b, h2v_w, h2v_b, out);
}